// Round 3
// baseline (330.956 us; speedup 1.0000x reference)
//
#include <hip/hip_runtime.h>
#include <math.h>

#define EMB 1024
#define NB 4
#define SQ 2048
#define TOK (NB*SQ)   // 8192

typedef __attribute__((ext_vector_type(8))) short bhalf8;   // 8 bf16 (4 VGPRs)
typedef __attribute__((ext_vector_type(4))) float f32x4;

__device__ __forceinline__ unsigned short f32_to_bf16(float f) {
    unsigned int u = __float_as_uint(f);
    u += 0x7FFFu + ((u >> 16) & 1u);       // round-to-nearest-even
    return (unsigned short)(u >> 16);
}
__device__ __forceinline__ float bf16_to_f32(unsigned short h) {
    return __uint_as_float(((unsigned int)h) << 16);
}
__device__ __forceinline__ unsigned short f32_to_f16(float f) {
    union { _Float16 h; unsigned short u; } c; c.h = (_Float16)f; return c.u;
}
__device__ __forceinline__ float f16_to_f32(unsigned short u) {
    union { _Float16 h; unsigned short u; } c; c.u = u; return (float)c.h;
}

// ---------------- fused fp32 -> bf16 conversion: x (8192 blocks) + weights (5120) ----------------
__global__ __launch_bounds__(256) void convert_all_kernel(
    const float* __restrict__ x,  unsigned short* __restrict__ x_bf,
    const float* __restrict__ rot, const float* __restrict__ ent,
    const float* __restrict__ gw, unsigned short* __restrict__ w_bf) {
    const int EE4 = EMB * EMB / 4;
    const float* src;
    unsigned short* dst;
    float scale = 1.0f;
    int j;
    if (blockIdx.x < TOK*EMB/4/256) {
        src = x; dst = x_bf; j = blockIdx.x * 256 + threadIdx.x;
        float4 v = ((const float4*)src)[j];
        ushort4 o = { f32_to_bf16(v.x), f32_to_bf16(v.y), f32_to_bf16(v.z), f32_to_bf16(v.w) };
        ((ushort4*)dst)[j] = o;
        return;
    }
    const int i = (blockIdx.x - TOK*EMB/4/256) * 256 + threadIdx.x;   // over 5*EE4
    j = i; dst = w_bf;
    if (i < 3 * EE4) {
        src = rot;
        if (i < EE4) scale = 0.125f;                // 1/sqrt(64) folded into q-rows
    } else if (i < 4 * EE4) { src = ent; j = i - 3 * EE4; }
    else                    { src = gw;  j = i - 4 * EE4; }
    float4 v = ((const float4*)src)[j];
    ushort4 o;
    o.x = f32_to_bf16(v.x * scale);
    o.y = f32_to_bf16(v.y * scale);
    o.z = f32_to_bf16(v.z * scale);
    o.w = f32_to_bf16(v.w * scale);
    ((ushort4*)dst)[i] = o;
}

// ---------------- async global->LDS 16B staging helper ----------------
__device__ __forceinline__ void async_load16(const unsigned short* gp, unsigned short* lp) {
    __builtin_amdgcn_global_load_lds(
        (const __attribute__((address_space(1))) unsigned int*)gp,
        (__attribute__((address_space(3))) unsigned int*)lp,
        16, 0, 0);
}

// =====================================================================================
// Baseline 128x128 NT GEMM (m97 structure): known-good, 4 blocks/CU co-residency
// provides the inter-block overlap that masks barrier drains. Used for K1/K4/K5/K6.
// MODE 0: bf16 C; MODE 1: f16 C; MODE 2: Fout = sigmoid(acc) * bf16(Obf)
// =====================================================================================
template <int MODE>
__global__ __launch_bounds__(256) void gemm_nt_128(
    const unsigned short* __restrict__ A,
    const unsigned short* __restrict__ B,
    void* __restrict__ C,
    const unsigned short* __restrict__ Obf,
    float* __restrict__ Fout,
    int M, int N, int K, int lda, int ldb, int ldc,
    long sA, long sB, long sC)
{
    __shared__ __align__(16) unsigned short As[128*64];   // 16 KB
    __shared__ __align__(16) unsigned short Bs[128*64];

    const int bz = blockIdx.z;
    const unsigned short* Ab = A + (long)bz * sA;
    const unsigned short* Bb = B + (long)bz * sB;
    const int bm = blockIdx.x * 128;
    const int bn = blockIdx.y * 128;
    const int t = threadIdx.x;
    const int w = t >> 6;        // wave 0..3
    const int l = t & 63;        // lane
    const int srow8 = l >> 3;
    const int scol  = (((l & 7) ^ ((l >> 3) & 7)) * 8);

    f32x4 zero = {0.f, 0.f, 0.f, 0.f};
    f32x4 acc[4][4];
    #pragma unroll
    for (int i = 0; i < 4; ++i)
        #pragma unroll
        for (int j = 0; j < 4; ++j) acc[i][j] = zero;

    const int wm = (w >> 1) * 64;
    const int wn = (w & 1) * 64;
    const int fr = l & 15;
    const int kqs0 = ((((l >> 4)    ) ^ (l & 7)) * 8);
    const int kqs1 = (((4 + (l >> 4)) ^ (l & 7)) * 8);

    const int nkt = K >> 6;
    for (int kt = 0; kt < nkt; ++kt) {
        const int k0 = kt << 6;
        __syncthreads();
        #pragma unroll
        for (int r = 0; r < 4; ++r) {
            const int rr = (r*4 + w) * 8 + srow8;
            async_load16(Ab + (long)(bm + rr) * lda + (k0 + scol), As + (r*4 + w) * 512);
            async_load16(Bb + (long)(bn + rr) * ldb + (k0 + scol), Bs + (r*4 + w) * 512);
        }
        __syncthreads();

        #pragma unroll
        for (int h = 0; h < 2; ++h) {
            const int kq = h ? kqs1 : kqs0;
            bhalf8 af[4], bfr[4];
            #pragma unroll
            for (int mi = 0; mi < 4; ++mi)
                af[mi] = *(const bhalf8*)(As + (wm + mi*16 + fr) * 64 + kq);
            #pragma unroll
            for (int ni = 0; ni < 4; ++ni)
                bfr[ni] = *(const bhalf8*)(Bs + (wn + ni*16 + fr) * 64 + kq);
            #pragma unroll
            for (int mi = 0; mi < 4; ++mi)
                #pragma unroll
                for (int ni = 0; ni < 4; ++ni)
                    acc[mi][ni] = __builtin_amdgcn_mfma_f32_16x16x32_bf16(
                        af[mi], bfr[ni], acc[mi][ni], 0, 0, 0);
        }
    }

    const int crow = (l >> 4) * 4;
    const int ccol = l & 15;
    #pragma unroll
    for (int mi = 0; mi < 4; ++mi) {
        #pragma unroll
        for (int ni = 0; ni < 4; ++ni) {
            #pragma unroll
            for (int r = 0; r < 4; ++r) {
                const int gr = bm + wm + mi*16 + crow + r;
                const int gc = bn + wn + ni*16 + ccol;
                const float v = acc[mi][ni][r];
                const long idx = (long)gr * ldc + gc;
                if (MODE == 0) {
                    ((unsigned short*)C)[(long)bz*sC + idx] = f32_to_bf16(v);
                } else if (MODE == 1) {
                    ((unsigned short*)C)[(long)bz*sC + idx] = f32_to_f16(v);
                } else {
                    const float o = bf16_to_f32(Obf[idx]);
                    const float g = 1.0f / (1.0f + __expf(-v));
                    Fout[idx] = g * o;
                }
            }
        }
    }
}

// =====================================================================================
// v3: 256x256, BK=64, 8 waves, SOFTWARE-PIPELINED REGISTER READS (reads one phase
// ahead into ping-pong reg sets) so the LDS pipe retires reads UNDER the MFMA cluster
// instead of alternating with it. Compiler's automatic counted lgkmcnt provides the
// T4-style partial wait (older reads done, newer still in flight).
// Phase p: { reads for p+1 ; stage 1 half-tile ; s_barrier ; MFMA(p) }.
// Reg sets: Aa/Ab ping-pong within tile (A(0)->Aa at P4 of prev tile, A(1)->Ab @P1,
// A(2)->Aa @P2, A(3)->Ab @P3); B double-buffered across tiles (B(t+1) read @P4 after
// the vmcnt(6)+barrier guarantees tile t+1 landed). Tile loop unrolled x2 for static
// reg-set roles (rule #20). Stage stream + vmcnt(6) identical to R2 (verified correct).
// Requires nkt even, >= 2. Used for K2 only (256 blocks = perfect fill).
// =====================================================================================

#define BARF() asm volatile("s_barrier" ::: "memory")
#define VMC6() asm volatile("s_waitcnt vmcnt(6)" ::: "memory")
#define VMC0() asm volatile("s_waitcnt vmcnt(0)" ::: "memory")

#define STAGE_A(buf, half, kofs) do { \
    async_load16(aG0 + (half)*aH + (kofs), &As[buf][(half)*8192 +        w*512]); \
    async_load16(aG1 + (half)*aH + (kofs), &As[buf][(half)*8192 + 4096 + w*512]); \
} while (0)
#define STAGE_B(buf, half, kofs) do { \
    async_load16(bG0 + (half)*bH + (kofs), &Bs[buf][(half)*8192 +        w*512]); \
    async_load16(bG1 + (half)*bH + (kofs), &Bs[buf][(half)*8192 + 4096 + w*512]); \
} while (0)

#define RD_A(dst, base, p) do { \
    dst[0][0] = *(const bhalf8*)((base) + ((p)*2    )*1024 + kqs0); \
    dst[0][1] = *(const bhalf8*)((base) + ((p)*2    )*1024 + kqs1); \
    dst[1][0] = *(const bhalf8*)((base) + ((p)*2 + 1)*1024 + kqs0); \
    dst[1][1] = *(const bhalf8*)((base) + ((p)*2 + 1)*1024 + kqs1); \
} while (0)

#define RD_B(dst, base) do { \
    _Pragma("unroll") \
    for (int ni_ = 0; ni_ < 4; ++ni_) { \
        dst[ni_][0] = *(const bhalf8*)((base) + ni_*1024 + kqs0); \
        dst[ni_][1] = *(const bhalf8*)((base) + ni_*1024 + kqs1); \
    } \
} while (0)

#define MFMA8(p, Aset, Bset) do { \
    __builtin_amdgcn_s_setprio(1); \
    _Pragma("unroll") \
    for (int h_ = 0; h_ < 2; ++h_) \
        _Pragma("unroll") \
        for (int mi_ = 0; mi_ < 2; ++mi_) \
            _Pragma("unroll") \
            for (int ni_ = 0; ni_ < 4; ++ni_) \
                acc[(p)*2 + mi_][ni_] = __builtin_amdgcn_mfma_f32_16x16x32_bf16( \
                    Aset[mi_][h_], Bset[ni_][h_], acc[(p)*2 + mi_][ni_], 0, 0, 0); \
    __builtin_amdgcn_s_setprio(0); \
} while (0)

// One K-tile, 4 phases. Bc = B regs for THIS tile, Bn = set receiving B(t+1).
#define TILE_V3(kt, CUR, Bc, Bn) do { \
    const int cur_ = (CUR); const int nxt_ = cur_ ^ 1; \
    const bool s1 = (kt) + 1 < nkt; \
    const bool s2 = (kt) + 2 < nkt; \
    const int k1 = ((kt) + 1) << 6; \
    const int k2 = ((kt) + 2) << 6; \
    const unsigned short* aRd  = &As[cur_][(wm + fr) * 64]; \
    const unsigned short* aRdN = &As[nxt_][(wm + fr) * 64]; \
    const unsigned short* bRdN = &Bs[nxt_][(wn + fr) * 64]; \
    /* P1: read A(1)->Ab; stage A-hi(t+1)->nxt; bar; MFMA(0) = Aa x Bc */ \
    RD_A(Ab, aRd, 1); \
    if (s1) STAGE_A(nxt_, 1, k1); \
    BARF(); \
    MFMA8(0, Aa, Bc); \
    /* P2: read A(2)->Aa; stage B-lo(t+2)->cur (B slots free since P4(t-1)); MFMA(1) */ \
    RD_A(Aa, aRd, 2); \
    if (s2) STAGE_B(cur_, 0, k2); \
    BARF(); \
    MFMA8(1, Ab, Bc); \
    /* P3: read A(3)->Ab; stage B-hi(t+2)->cur; MFMA(2) */ \
    RD_A(Aa2, aRd, 3); \
    if (s2) STAGE_B(cur_, 1, k2); \
    BARF(); \
    MFMA8(2, Aa, Bc); \
    /* P4: stage A-lo(t+2)->cur; vmcnt; bar (tile t+1 now fully in LDS); read */ \
    /* A(0)(t+1)->Aa + B(t+1)->Bn; MFMA(3) = Aa2 x Bc overlaps those reads */ \
    if (s2) { STAGE_A(cur_, 0, k2); VMC6(); } else { VMC0(); } \
    BARF(); \
    if (s1) { RD_A(Aa, aRdN, 0); RD_B(Bn, bRdN); } \
    MFMA8(3, Aa2, Bc); \
} while (0)

template <int MODE>
__global__ __launch_bounds__(512, 2) void gemm_nt_v3(
    const unsigned short* __restrict__ A,
    const unsigned short* __restrict__ B,
    void* __restrict__ C,
    const unsigned short* __restrict__ Obf,
    float* __restrict__ Fout,
    int M, int N, int K, int lda, int ldb, int ldc,
    long sA, long sB, long sC)
{
    __shared__ __align__(16) unsigned short As[2][16384];   // 64 KB  [buf][256*64]
    __shared__ __align__(16) unsigned short Bs[2][16384];   // 64 KB

    const int bz = blockIdx.z;
    const unsigned short* Ab_ = A + (long)bz * sA;
    const unsigned short* Bb_ = B + (long)bz * sB;
    const int bm = blockIdx.x * 256;
    const int bn = blockIdx.y * 256;
    const int t = threadIdx.x;
    const int w = t >> 6;        // wave 0..7
    const int l = t & 63;        // lane

    const int srow = l >> 3;
    const int scol = (((l & 7) ^ (l >> 3)) * 8);

    const int fr = l & 15;
    const int kqs0 = ((((l >> 4)    ) ^ (l & 7)) * 8);
    const int kqs1 = (((4 + (l >> 4)) ^ (l & 7)) * 8);

    const int wm = (w >> 2) * 128;   // WARPS_M = 2
    const int wn = (w & 3) * 64;     // WARPS_N = 4

    f32x4 acc[8][4];
    f32x4 zero = {0.f, 0.f, 0.f, 0.f};
    #pragma unroll
    for (int i = 0; i < 8; ++i)
        #pragma unroll
        for (int j = 0; j < 4; ++j) acc[i][j] = zero;

    const unsigned short* aG0 = Ab_ + (long)(bm + (    w)*8 + srow) * lda + scol;
    const unsigned short* aG1 = Ab_ + (long)(bm + (8 + w)*8 + srow) * lda + scol;
    const unsigned short* bG0 = Bb_ + (long)(bn + (    w)*8 + srow) * ldb + scol;
    const unsigned short* bG1 = Bb_ + (long)(bn + (8 + w)*8 + srow) * ldb + scol;
    const long aH = (long)128 * lda;
    const long bH = (long)128 * ldb;

    const int nkt = K >> 6;            // even, >= 2 required (16 here)

    // fragment register sets (all statically indexed)
    bhalf8 Aa[2][2], Ab[2][2], Aa2[2][2];
    bhalf8 B0[4][2], B1[4][2];

    // ---- prologue: stage tile0 (8 loads) + tile1 {B-lo, B-hi, A-lo} (6 loads) ----
    STAGE_A(0, 0, 0);  STAGE_A(0, 1, 0);
    STAGE_B(0, 0, 0);  STAGE_B(0, 1, 0);
    STAGE_B(1, 0, 64); STAGE_B(1, 1, 64);
    STAGE_A(1, 0, 64);
    VMC6();                            // tile0 landed; tile1's 6 in flight
    BARF();
    {   // pre-read tile0's A(0) + B into Aa/B0 (land during tile0's P1)
        const unsigned short* aRd0 = &As[0][(wm + fr) * 64];
        const unsigned short* bRd0 = &Bs[0][(wn + fr) * 64];
        RD_A(Aa, aRd0, 0);
        RD_B(B0, bRd0);
    }

    for (int kt = 0; kt < nkt; kt += 2) {
        TILE_V3(kt,     0, B0, B1);
        TILE_V3(kt + 1, 1, B1, B0);
    }

    // C/D layout (m89-verified): col = lane&15, row = (lane>>4)*4 + reg
    const int crow = (l >> 4) * 4;
    const int ccol = l & 15;
    #pragma unroll
    for (int mi = 0; mi < 8; ++mi) {
        #pragma unroll
        for (int ni = 0; ni < 4; ++ni) {
            #pragma unroll
            for (int r = 0; r < 4; ++r) {
                const int gr = bm + wm + mi*16 + crow + r;
                const int gc = bn + wn + ni*16 + ccol;
                const float v = acc[mi][ni][r];
                const long idx = (long)gr * ldc + gc;
                if (MODE == 0) {
                    ((unsigned short*)C)[(long)bz*sC + idx] = f32_to_bf16(v);
                } else if (MODE == 1) {
                    ((unsigned short*)C)[(long)bz*sC + idx] = f32_to_f16(v);
                } else {
                    const float o = bf16_to_f32(Obf[idx]);
                    const float g = 1.0f / (1.0f + __expf(-v));
                    Fout[idx] = g * o;
                }
            }
        }
    }
}

#undef BARF
#undef VMC6
#undef VMC0
#undef STAGE_A
#undef STAGE_B
#undef RD_A
#undef RD_B
#undef MFMA8
#undef TILE_V3

// ---------------- row softmax: f16 scores in, bf16 attn out (row len 2048) ----------------
__global__ __launch_bounds__(256) void softmax_kernel(const unsigned short* __restrict__ sc,
                                                      unsigned short* __restrict__ attn) {
    const long row = blockIdx.x;
    const unsigned short* p = sc + row * SQ;
    unsigned short* q = attn + row * SQ;
    const int t = threadIdx.x;
    const int w = t >> 6, l = t & 63;
    union { bhalf8 v; unsigned short u[8]; } in;
    in.v = ((const bhalf8*)p)[t];
    float f[8];
    float m = -1e30f;
    #pragma unroll
    for (int j = 0; j < 8; ++j) { f[j] = f16_to_f32(in.u[j]); m = fmaxf(m, f[j]); }
    #pragma unroll
    for (int off = 32; off; off >>= 1) m = fmaxf(m, __shfl_xor(m, off));
    __shared__ float smax[4], ssum[4];
    if (l == 0) smax[w] = m;
    __syncthreads();
    m = fmaxf(fmaxf(smax[0], smax[1]), fmaxf(smax[2], smax[3]));
    float s = 0.f;
    #pragma unroll
    for (int j = 0; j < 8; ++j) { f[j] = __expf(f[j] - m); s += f[j]; }
    #pragma unroll
    for (int off = 32; off; off >>= 1) s += __shfl_xor(s, off);
    if (l == 0) ssum[w] = s;
    __syncthreads();
    const float inv = 1.0f / (ssum[0] + ssum[1] + ssum[2] + ssum[3]);
    union { bhalf8 v; unsigned short u[8]; } o;
    #pragma unroll
    for (int j = 0; j < 8; ++j) o.u[j] = f32_to_bf16(f[j] * inv);
    ((bhalf8*)q)[t] = o.v;
}

// ---------------- transpose v (per batch: (2048 x 1024, ld 3072) -> (1024 x 2048)) ----------------
__global__ void transpose_v(const unsigned short* __restrict__ qkv,
                            unsigned short* __restrict__ vT) {
    __shared__ unsigned short tile[32][33];
    const int b = blockIdx.z;
    const unsigned short* v = qkv + (long)b * SQ * (3*EMB) + 2*EMB;
    const int e = blockIdx.x * 32 + threadIdx.x;
    const int s = blockIdx.y * 32 + threadIdx.y;
    tile[threadIdx.y][threadIdx.x] = v[(long)s * (3*EMB) + e];
    __syncthreads();
    const int so = blockIdx.y * 32 + threadIdx.x;
    const int eo = blockIdx.x * 32 + threadIdx.y;
    vT[(long)b * EMB * SQ + (long)eo * SQ + so] = tile[threadIdx.x][threadIdx.y];
}

extern "C" void kernel_launch(void* const* d_in, const int* in_sizes, int n_in,
                              void* d_out, int out_size, void* d_ws, size_t ws_size,
                              hipStream_t stream) {
    const float* rot = (const float*)d_in[0];   // (3E, E) row-major
    const float* ent = (const float*)d_in[1];   // (E, E)
    const float* x   = (const float*)d_in[2];   // (B, S, E)
    const float* gw  = (const float*)d_in[3];   // (E, E)
    float* outp = (float*)d_out;
    char* ws = (char*)d_ws;

    size_t off = 0;
    unsigned short* x_bf    = (unsigned short*)(ws + off); off += (size_t)TOK*EMB*2;     // 16 MB
    unsigned short* wqkv_bf = (unsigned short*)(ws + off); off += (size_t)3*EMB*EMB*2;   // 6 MB
    unsigned short* wout_bf = (unsigned short*)(ws + off); off += (size_t)EMB*EMB*2;     // 2 MB
    unsigned short* gate_bf = (unsigned short*)(ws + off); off += (size_t)EMB*EMB*2;     // 2 MB
    unsigned short* qkv_bf  = (unsigned short*)(ws + off); off += (size_t)TOK*3*EMB*2;   // 48 MB
    unsigned short* vT_bf   = (unsigned short*)(ws + off); off += (size_t)NB*EMB*SQ*2;   // 16 MB
    unsigned short* sc_f16  = (unsigned short*)(ws + off); off += (size_t)NB*SQ*SQ*2;    // 32 MB
    // Aliases (lifetimes disjoint, all launches sequential on one stream):
    unsigned short* attn_bf = qkv_bf;                        // qkv dead after K2; attn live K3->K4
    unsigned short* ao_bf   = x_bf;                          // x dead after K1; ao live K4->K5
    unsigned short* out_bf  = qkv_bf + (size_t)NB*SQ*SQ;     // qkv[32MB:48MB], live K5->K6

    // K0: all converts in one launch
    convert_all_kernel<<<dim3(TOK*EMB/4/256 + 5*EMB*EMB/4/256), dim3(256), 0, stream>>>(
        x, x_bf, rot, ent, gw, wqkv_bf);

    // K1: qkv = x @ w_qkv^T   (8192 x 3072, K=1024) -> bf16   [1536 blocks, 128^2]
    gemm_nt_128<0><<<dim3(TOK/128, 3*EMB/128, 1), dim3(256), 0, stream>>>(
        x_bf, wqkv_bf, qkv_bf, nullptr, nullptr,
        TOK, 3*EMB, EMB, EMB, EMB, 3*EMB, 0, 0, 0);

    // transpose v -> vT (per batch E x S)
    transpose_v<<<dim3(EMB/32, SQ/32, NB), dim3(32, 32), 0, stream>>>(qkv_bf, vT_bf);

    // K2: scores = q @ k^T per batch (2048 x 2048, K=1024) -> f16
    //     [v3 8-phase experiment: 256 blocks = perfect 1-round fill]
    gemm_nt_v3<1><<<dim3(SQ/256, SQ/256, NB), dim3(512), 0, stream>>>(
        qkv_bf, qkv_bf + EMB, sc_f16, nullptr, nullptr,
        SQ, SQ, EMB, 3*EMB, 3*EMB, SQ,
        (long)SQ*3*EMB, (long)SQ*3*EMB, (long)SQ*SQ);

    // K3: softmax rows (f16 in, bf16 out)
    softmax_kernel<<<dim3(NB*SQ), dim3(256), 0, stream>>>(sc_f16, attn_bf);

    // K4: attn_out = attn @ v per batch (2048 x 1024, K=2048)  [512 blocks, 128^2]
    gemm_nt_128<0><<<dim3(SQ/128, EMB/128, NB), dim3(256), 0, stream>>>(
        attn_bf, vT_bf, ao_bf, nullptr, nullptr,
        SQ, EMB, SQ, SQ, SQ, EMB,
        (long)SQ*SQ, (long)EMB*SQ, (long)SQ*EMB);

    // K5: out = attn_out @ w_out^T (8192 x 1024, K=1024) -> bf16  [512 blocks, 128^2]
    gemm_nt_128<0><<<dim3(TOK/128, EMB/128, 1), dim3(256), 0, stream>>>(
        ao_bf, wout_bf, out_bf, nullptr, nullptr,
        TOK, EMB, EMB, EMB, EMB, EMB, 0, 0, 0);

    // K6: result = sigmoid(out @ gate_w^T) * out_bf -> fp32 d_out  [512 blocks, 128^2]
    gemm_nt_128<2><<<dim3(TOK/128, EMB/128, 1), dim3(256), 0, stream>>>(
        out_bf, gate_bf, nullptr, out_bf, outp,
        TOK, EMB, EMB, EMB, EMB, EMB, 0, 0, 0);
}

// Round 10
// 316.670 us; speedup vs baseline: 1.0451x; 1.0451x over previous
//
#include <hip/hip_runtime.h>
#include <math.h>

#define EMB 1024
#define NB 4
#define SQ 2048
#define TOK (NB*SQ)   // 8192

typedef __attribute__((ext_vector_type(8))) short bhalf8;   // 8 bf16 (4 VGPRs)
typedef __attribute__((ext_vector_type(4))) float f32x4;

__device__ __forceinline__ unsigned short f32_to_bf16(float f) {
    unsigned int u = __float_as_uint(f);
    u += 0x7FFFu + ((u >> 16) & 1u);       // round-to-nearest-even
    return (unsigned short)(u >> 16);
}
__device__ __forceinline__ float bf16_to_f32(unsigned short h) {
    return __uint_as_float(((unsigned int)h) << 16);
}

// ---------------- fused fp32 -> bf16 conversion + Sf zeroing ----------------
// x (8192 blocks) + weights (5120 blocks) + Sf zero (8 blocks)
__global__ __launch_bounds__(256) void convert_all_kernel(
    const float* __restrict__ x,  unsigned short* __restrict__ x_bf,
    const float* __restrict__ rot, const float* __restrict__ ent,
    const float* __restrict__ gw, unsigned short* __restrict__ w_bf,
    float* __restrict__ Sf) {
    const int EE4 = EMB * EMB / 4;
    const int XB = TOK*EMB/4/256;      // 8192 blocks for x
    const int WB = 5*EE4/256;          // 5120 blocks for weights
    const float* src;
    unsigned short* dst;
    float scale = 1.0f;
    int j;
    if (blockIdx.x < XB) {
        src = x; dst = x_bf; j = blockIdx.x * 256 + threadIdx.x;
        float4 v = ((const float4*)src)[j];
        ushort4 o = { f32_to_bf16(v.x), f32_to_bf16(v.y), f32_to_bf16(v.z), f32_to_bf16(v.w) };
        ((ushort4*)dst)[j] = o;
        return;
    }
    if (blockIdx.x >= XB + WB) {       // zero Sf (NB*SQ floats = 2048 float4)
        const int z = (blockIdx.x - XB - WB) * 256 + threadIdx.x;
        float4 zz = {0.f, 0.f, 0.f, 0.f};
        ((float4*)Sf)[z] = zz;
        return;
    }
    const int i = (blockIdx.x - XB) * 256 + threadIdx.x;   // over 5*EE4
    j = i; dst = w_bf;
    if (i < 3 * EE4) {
        src = rot;
        if (i < EE4) scale = 0.125f;                // 1/sqrt(64) folded into q-rows
    } else if (i < 4 * EE4) { src = ent; j = i - 3 * EE4; }
    else                    { src = gw;  j = i - 4 * EE4; }
    float4 v = ((const float4*)src)[j];
    ushort4 o;
    o.x = f32_to_bf16(v.x * scale);
    o.y = f32_to_bf16(v.y * scale);
    o.z = f32_to_bf16(v.z * scale);
    o.w = f32_to_bf16(v.w * scale);
    ((ushort4*)dst)[i] = o;
}

// ---------------- async global->LDS 16B staging helper ----------------
__device__ __forceinline__ void async_load16(const unsigned short* gp, unsigned short* lp) {
    __builtin_amdgcn_global_load_lds(
        (const __attribute__((address_space(1))) unsigned int*)gp,
        (__attribute__((address_space(3))) unsigned int*)lp,
        16, 0, 0);
}

// =====================================================================================
// 128x128 NT GEMM (m97 structure, measured-optimal tile for this structure).
// C[m,n] = sum_k A[m,k]*B[n,k], bf16 in, fp32 acc. Zero bank conflicts (verified).
// Epilogue MODEs:
//   0: C bf16 <- v                                  (K5)
//   1: C bf16 <- exp(v-16); row-sums atomicAdd->Sf  (K2: unnormalized softmax P)
//   2: Fout f32 <- sigmoid(v) * bf16(Obf[idx])      (K6: final gate)
//   3: C bf16 <- v / Sf[row]                        (K4: normalize attn output)
//   5: bn<2048: C bf16 <- v (q,k);  bn>=2048: transposed ushort4 write to Vt (v)
// =====================================================================================
template <int MODE>
__global__ __launch_bounds__(256) void gemm_nt_128(
    const unsigned short* __restrict__ A,
    const unsigned short* __restrict__ B,
    void* __restrict__ C,
    const unsigned short* __restrict__ Obf,
    float* __restrict__ Fout,
    float* __restrict__ Sf,
    unsigned short* __restrict__ Vt,
    int M, int N, int K, int lda, int ldb, int ldc,
    long sA, long sB, long sC)
{
    __shared__ __align__(16) unsigned short As[128*64];   // 16 KB
    __shared__ __align__(16) unsigned short Bs[128*64];

    const int bz = blockIdx.z;
    const unsigned short* Ab = A + (long)bz * sA;
    const unsigned short* Bb = B + (long)bz * sB;
    const int bm = blockIdx.x * 128;
    const int bn = blockIdx.y * 128;
    const int t = threadIdx.x;
    const int w = t >> 6;        // wave 0..3
    const int l = t & 63;        // lane
    const int srow8 = l >> 3;
    const int scol  = (((l & 7) ^ ((l >> 3) & 7)) * 8);

    f32x4 zero = {0.f, 0.f, 0.f, 0.f};
    f32x4 acc[4][4];
    #pragma unroll
    for (int i = 0; i < 4; ++i)
        #pragma unroll
        for (int j = 0; j < 4; ++j) acc[i][j] = zero;

    const int wm = (w >> 1) * 64;
    const int wn = (w & 1) * 64;
    const int fr = l & 15;
    const int kqs0 = ((((l >> 4)    ) ^ (l & 7)) * 8);
    const int kqs1 = (((4 + (l >> 4)) ^ (l & 7)) * 8);

    const int nkt = K >> 6;
    for (int kt = 0; kt < nkt; ++kt) {
        const int k0 = kt << 6;
        __syncthreads();
        #pragma unroll
        for (int r = 0; r < 4; ++r) {
            const int rr = (r*4 + w) * 8 + srow8;
            async_load16(Ab + (long)(bm + rr) * lda + (k0 + scol), As + (r*4 + w) * 512);
            async_load16(Bb + (long)(bn + rr) * ldb + (k0 + scol), Bs + (r*4 + w) * 512);
        }
        __syncthreads();

        #pragma unroll
        for (int h = 0; h < 2; ++h) {
            const int kq = h ? kqs1 : kqs0;
            bhalf8 af[4], bfr[4];
            #pragma unroll
            for (int mi = 0; mi < 4; ++mi)
                af[mi] = *(const bhalf8*)(As + (wm + mi*16 + fr) * 64 + kq);
            #pragma unroll
            for (int ni = 0; ni < 4; ++ni)
                bfr[ni] = *(const bhalf8*)(Bs + (wn + ni*16 + fr) * 64 + kq);
            #pragma unroll
            for (int mi = 0; mi < 4; ++mi)
                #pragma unroll
                for (int ni = 0; ni < 4; ++ni)
                    acc[mi][ni] = __builtin_amdgcn_mfma_f32_16x16x32_bf16(
                        af[mi], bfr[ni], acc[mi][ni], 0, 0, 0);
        }
    }

    // C/D layout (m89-verified): col = lane&15, row = (lane>>4)*4 + reg
    const int crow = (l >> 4) * 4;
    const int ccol = l & 15;

    float psum[4][4];                 // MODE 1: per-(mi,r) partial row sums
    if (MODE == 1) {
        #pragma unroll
        for (int mi = 0; mi < 4; ++mi)
            #pragma unroll
            for (int r = 0; r < 4; ++r) psum[mi][r] = 0.f;
    }
    float rinv[4][4];                 // MODE 3: per-(mi,r) 1/rowsum
    if (MODE == 3) {
        #pragma unroll
        for (int mi = 0; mi < 4; ++mi)
            #pragma unroll
            for (int r = 0; r < 4; ++r)
                rinv[mi][r] = 1.0f / Sf[(long)bz * SQ + bm + wm + mi*16 + crow + r];
    }

    const bool vtile = (MODE == 5) && (bn >= 2*EMB);   // block-uniform

    #pragma unroll
    for (int mi = 0; mi < 4; ++mi) {
        #pragma unroll
        for (int ni = 0; ni < 4; ++ni) {
            if (MODE == 5 && vtile) {
                // transposed v write: vT[b][e][s], e = gc-2048, s = token row in batch
                const int gc = bn + wn + ni*16 + ccol;        // 2048..3071
                const int e  = gc - 2*EMB;
                const int b  = bm >> 11;                      // SQ = 2048
                const int s0 = (bm & (SQ-1)) + wm + mi*16 + crow;
                ushort4 o;
                o.x = f32_to_bf16(acc[mi][ni][0]);
                o.y = f32_to_bf16(acc[mi][ni][1]);
                o.z = f32_to_bf16(acc[mi][ni][2]);
                o.w = f32_to_bf16(acc[mi][ni][3]);
                *(ushort4*)(Vt + ((long)(b*EMB + e)) * SQ + s0) = o;
                continue;
            }
            #pragma unroll
            for (int r = 0; r < 4; ++r) {
                const int gr = bm + wm + mi*16 + crow + r;
                const int gc = bn + wn + ni*16 + ccol;
                const float v = acc[mi][ni][r];
                const long idx = (long)gr * ldc + gc;
                if (MODE == 0 || MODE == 5) {
                    ((unsigned short*)C)[(long)bz*sC + idx] = f32_to_bf16(v);
                } else if (MODE == 1) {
                    const unsigned short p = f32_to_bf16(__expf(v - 16.0f));
                    ((unsigned short*)C)[(long)bz*sC + idx] = p;
                    psum[mi][r] += bf16_to_f32(p);   // sum the ROUNDED value (matches K4 read)
                } else if (MODE == 3) {
                    ((unsigned short*)C)[(long)bz*sC + idx] = f32_to_bf16(v * rinv[mi][r]);
                } else {   // MODE 2
                    const float o = bf16_to_f32(Obf[idx]);
                    const float g = 1.0f / (1.0f + __expf(-v));
                    Fout[idx] = g * o;
                }
            }
        }
    }

    if (MODE == 1) {
        // reduce across the 16 ccol lanes of each crow group, 1 atomic per group
        #pragma unroll
        for (int mi = 0; mi < 4; ++mi) {
            #pragma unroll
            for (int r = 0; r < 4; ++r) {
                float s_ = psum[mi][r];
                s_ += __shfl_xor(s_, 1);
                s_ += __shfl_xor(s_, 2);
                s_ += __shfl_xor(s_, 4);
                s_ += __shfl_xor(s_, 8);
                if ((l & 15) == 0)
                    atomicAdd(&Sf[(long)bz * SQ + bm + wm + mi*16 + crow + r], s_);
            }
        }
    }
}

extern "C" void kernel_launch(void* const* d_in, const int* in_sizes, int n_in,
                              void* d_out, int out_size, void* d_ws, size_t ws_size,
                              hipStream_t stream) {
    const float* rot = (const float*)d_in[0];   // (3E, E) row-major
    const float* ent = (const float*)d_in[1];   // (E, E)
    const float* x   = (const float*)d_in[2];   // (B, S, E)
    const float* gw  = (const float*)d_in[3];   // (E, E)
    float* outp = (float*)d_out;
    char* ws = (char*)d_ws;

    size_t off = 0;
    unsigned short* x_bf    = (unsigned short*)(ws + off); off += (size_t)TOK*EMB*2;     // 16 MB
    unsigned short* wqkv_bf = (unsigned short*)(ws + off); off += (size_t)3*EMB*EMB*2;   // 6 MB
    unsigned short* wout_bf = (unsigned short*)(ws + off); off += (size_t)EMB*EMB*2;     // 2 MB
    unsigned short* gate_bf = (unsigned short*)(ws + off); off += (size_t)EMB*EMB*2;     // 2 MB
    unsigned short* qkv_bf  = (unsigned short*)(ws + off); off += (size_t)TOK*3*EMB*2;   // 48 MB
    unsigned short* vT_bf   = (unsigned short*)(ws + off); off += (size_t)NB*EMB*SQ*2;   // 16 MB
    unsigned short* p_bf    = (unsigned short*)(ws + off); off += (size_t)NB*SQ*SQ*2;    // 32 MB (P)
    float*          sf      = (float*)(ws + off);          off += (size_t)NB*SQ*4;       // 32 KB
    // Aliases (lifetimes disjoint, all launches sequential on one stream):
    unsigned short* ao_bf   = x_bf;                          // x dead after K1; ao live K4->K5
    unsigned short* out_bf  = qkv_bf + (size_t)NB*SQ*SQ;     // qkv dead after K2; out live K5->K6

    // K0: all converts + Sf zeroing in one launch
    convert_all_kernel<<<dim3(TOK*EMB/4/256 + 5*EMB*EMB/4/256 + NB*SQ/4/256), dim3(256),
                         0, stream>>>(x, x_bf, rot, ent, gw, wqkv_bf, sf);

    // K1: qkv = x @ w_qkv^T (8192 x 3072, K=1024); q,k -> qkv_bf, v -> vT_bf transposed
    gemm_nt_128<5><<<dim3(TOK/128, 3*EMB/128, 1), dim3(256), 0, stream>>>(
        x_bf, wqkv_bf, qkv_bf, nullptr, nullptr, nullptr, vT_bf,
        TOK, 3*EMB, EMB, EMB, EMB, 3*EMB, 0, 0, 0);

    // K2: P = exp(q @ k^T - 16) per batch (2048 x 2048, K=1024) -> bf16 P + row sums
    gemm_nt_128<1><<<dim3(SQ/128, SQ/128, NB), dim3(256), 0, stream>>>(
        qkv_bf, qkv_bf + EMB, p_bf, nullptr, nullptr, sf, nullptr,
        SQ, SQ, EMB, 3*EMB, 3*EMB, SQ,
        (long)SQ*3*EMB, (long)SQ*3*EMB, (long)SQ*SQ);

    // K4: attn_out = (P @ v) / rowsum per batch (2048 x 1024, K=2048); B = vT (NT form)
    gemm_nt_128<3><<<dim3(SQ/128, EMB/128, NB), dim3(256), 0, stream>>>(
        p_bf, vT_bf, ao_bf, nullptr, nullptr, sf, nullptr,
        SQ, EMB, SQ, SQ, SQ, EMB,
        (long)SQ*SQ, (long)EMB*SQ, (long)SQ*EMB);

    // K5: out = attn_out @ w_out^T (8192 x 1024, K=1024) -> bf16
    gemm_nt_128<0><<<dim3(TOK/128, EMB/128, 1), dim3(256), 0, stream>>>(
        ao_bf, wout_bf, out_bf, nullptr, nullptr, nullptr, nullptr,
        TOK, EMB, EMB, EMB, EMB, EMB, 0, 0, 0);

    // K6: result = sigmoid(out @ gate_w^T) * out_bf -> fp32 d_out
    gemm_nt_128<2><<<dim3(TOK/128, EMB/128, 1), dim3(256), 0, stream>>>(
        out_bf, gate_bf, nullptr, out_bf, outp, nullptr, nullptr,
        TOK, EMB, EMB, EMB, EMB, EMB, 0, 0, 0);
}

// Round 11
// 300.807 us; speedup vs baseline: 1.1002x; 1.0527x over previous
//
#include <hip/hip_runtime.h>
#include <math.h>

#define EMB 1024
#define NB 4
#define SQ 2048
#define TOK (NB*SQ)   // 8192

typedef __attribute__((ext_vector_type(8))) short bhalf8;   // 8 bf16 (4 VGPRs)
typedef __attribute__((ext_vector_type(4))) float f32x4;

__device__ __forceinline__ unsigned short f32_to_bf16(float f) {
    unsigned int u = __float_as_uint(f);
    u += 0x7FFFu + ((u >> 16) & 1u);       // round-to-nearest-even
    return (unsigned short)(u >> 16);
}
__device__ __forceinline__ float bf16_to_f32(unsigned short h) {
    return __uint_as_float(((unsigned int)h) << 16);
}

// ---------------- fused fp32 -> bf16 conversion + Sf zeroing ----------------
__global__ __launch_bounds__(256) void convert_all_kernel(
    const float* __restrict__ x,  unsigned short* __restrict__ x_bf,
    const float* __restrict__ rot, const float* __restrict__ ent,
    const float* __restrict__ gw, unsigned short* __restrict__ w_bf,
    float* __restrict__ Sf) {
    const int EE4 = EMB * EMB / 4;
    const int XB = TOK*EMB/4/256;      // 8192 blocks for x
    const int WB = 5*EE4/256;          // 5120 blocks for weights
    const float* src;
    unsigned short* dst;
    float scale = 1.0f;
    int j;
    if (blockIdx.x < XB) {
        src = x; dst = x_bf; j = blockIdx.x * 256 + threadIdx.x;
        float4 v = ((const float4*)src)[j];
        ushort4 o = { f32_to_bf16(v.x), f32_to_bf16(v.y), f32_to_bf16(v.z), f32_to_bf16(v.w) };
        ((ushort4*)dst)[j] = o;
        return;
    }
    if (blockIdx.x >= XB + WB) {       // zero Sf (NB*SQ floats = 2048 float4)
        const int z = (blockIdx.x - XB - WB) * 256 + threadIdx.x;
        float4 zz = {0.f, 0.f, 0.f, 0.f};
        ((float4*)Sf)[z] = zz;
        return;
    }
    const int i = (blockIdx.x - XB) * 256 + threadIdx.x;   // over 5*EE4
    j = i; dst = w_bf;
    if (i < 3 * EE4) {
        src = rot;
        if (i < EE4) scale = 0.125f;                // 1/sqrt(64) folded into q-rows
    } else if (i < 4 * EE4) { src = ent; j = i - 3 * EE4; }
    else                    { src = gw;  j = i - 4 * EE4; }
    float4 v = ((const float4*)src)[j];
    ushort4 o;
    o.x = f32_to_bf16(v.x * scale);
    o.y = f32_to_bf16(v.y * scale);
    o.z = f32_to_bf16(v.z * scale);
    o.w = f32_to_bf16(v.w * scale);
    ((ushort4*)dst)[i] = o;
}

// ---------------- async global->LDS 16B staging helper ----------------
__device__ __forceinline__ void async_load16(const unsigned short* gp, unsigned short* lp) {
    __builtin_amdgcn_global_load_lds(
        (const __attribute__((address_space(1))) unsigned int*)gp,
        (__attribute__((address_space(3))) unsigned int*)lp,
        16, 0, 0);
}

// =====================================================================================
// 128xTN NT GEMM (m97 structure). TN=128: 4 waves of 64x64 (acc 4x4). TN=64: 4 waves
// of 64x32 (acc 4x2), 24 KB LDS -> used for the 512-block GEMMs to double blocks/CU
// (R10: grid-limited 2 blocks/CU = Occupancy 25% was the K4/K5/K6 bottleneck).
// C[m,n] = sum_k A[m,k]*B[n,k], bf16 in, fp32 acc. Zero bank conflicts (verified).
// Epilogue MODEs:
//   0: C bf16 <- v                                  (K5)
//   1: C bf16 <- exp(v-16); row-sums atomicAdd->Sf  (K2: unnormalized softmax P)
//   2: Fout f32 <- sigmoid(v) * bf16(Obf[idx])      (K6: final gate)
//   3: C bf16 <- v / Sf[row]                        (K4: normalize attn output)
//   5: bn<2048: C bf16 <- v (q,k);  bn>=2048: transposed ushort4 write to Vt (v)
// =====================================================================================
template <int MODE, int TN>
__global__ __launch_bounds__(256) void gemm_nt_128(
    const unsigned short* __restrict__ A,
    const unsigned short* __restrict__ B,
    void* __restrict__ C,
    const unsigned short* __restrict__ Obf,
    float* __restrict__ Fout,
    float* __restrict__ Sf,
    unsigned short* __restrict__ Vt,
    int M, int N, int K, int lda, int ldb, int ldc,
    long sA, long sB, long sC)
{
    constexpr int NI = TN / 32;                           // B-frags / wave (4 or 2)
    __shared__ __align__(16) unsigned short As[128*64];   // 16 KB
    __shared__ __align__(16) unsigned short Bs[TN*64];    // 16 or 8 KB

    const int bz = blockIdx.z;
    const unsigned short* Ab = A + (long)bz * sA;
    const unsigned short* Bb = B + (long)bz * sB;
    const int bm = blockIdx.x * 128;
    const int bn = blockIdx.y * TN;
    const int t = threadIdx.x;
    const int w = t >> 6;        // wave 0..3
    const int l = t & 63;        // lane
    const int srow8 = l >> 3;
    const int scol  = (((l & 7) ^ ((l >> 3) & 7)) * 8);

    f32x4 zero = {0.f, 0.f, 0.f, 0.f};
    f32x4 acc[4][NI];
    #pragma unroll
    for (int i = 0; i < 4; ++i)
        #pragma unroll
        for (int j = 0; j < NI; ++j) acc[i][j] = zero;

    const int wm = (w >> 1) * 64;
    const int wn = (w & 1) * (TN / 2);
    const int fr = l & 15;
    const int kqs0 = ((((l >> 4)    ) ^ (l & 7)) * 8);
    const int kqs1 = (((4 + (l >> 4)) ^ (l & 7)) * 8);

    const int nkt = K >> 6;
    for (int kt = 0; kt < nkt; ++kt) {
        const int k0 = kt << 6;
        __syncthreads();
        #pragma unroll
        for (int r = 0; r < 4; ++r) {
            const int rb = r*4 + w;                  // row-block 0..15 (8 rows each)
            const int rr = rb * 8 + srow8;
            async_load16(Ab + (long)(bm + rr) * lda + (k0 + scol), As + rb * 512);
            if (TN == 128 || rb < TN/8)
                async_load16(Bb + (long)(bn + rr) * ldb + (k0 + scol), Bs + rb * 512);
        }
        __syncthreads();

        #pragma unroll
        for (int h = 0; h < 2; ++h) {
            const int kq = h ? kqs1 : kqs0;
            bhalf8 af[4], bfr[NI];
            #pragma unroll
            for (int mi = 0; mi < 4; ++mi)
                af[mi] = *(const bhalf8*)(As + (wm + mi*16 + fr) * 64 + kq);
            #pragma unroll
            for (int ni = 0; ni < NI; ++ni)
                bfr[ni] = *(const bhalf8*)(Bs + (wn + ni*16 + fr) * 64 + kq);
            #pragma unroll
            for (int mi = 0; mi < 4; ++mi)
                #pragma unroll
                for (int ni = 0; ni < NI; ++ni)
                    acc[mi][ni] = __builtin_amdgcn_mfma_f32_16x16x32_bf16(
                        af[mi], bfr[ni], acc[mi][ni], 0, 0, 0);
        }
    }

    // C/D layout (m89-verified): col = lane&15, row = (lane>>4)*4 + reg
    const int crow = (l >> 4) * 4;
    const int ccol = l & 15;

    float psum[4][4];                 // MODE 1: per-(mi,r) partial row sums
    if (MODE == 1) {
        #pragma unroll
        for (int mi = 0; mi < 4; ++mi)
            #pragma unroll
            for (int r = 0; r < 4; ++r) psum[mi][r] = 0.f;
    }
    float rinv[4][4];                 // MODE 3: per-(mi,r) 1/rowsum
    if (MODE == 3) {
        #pragma unroll
        for (int mi = 0; mi < 4; ++mi)
            #pragma unroll
            for (int r = 0; r < 4; ++r)
                rinv[mi][r] = 1.0f / Sf[(long)bz * SQ + bm + wm + mi*16 + crow + r];
    }

    const bool vtile = (MODE == 5) && (bn >= 2*EMB);   // block-uniform

    #pragma unroll
    for (int mi = 0; mi < 4; ++mi) {
        #pragma unroll
        for (int ni = 0; ni < NI; ++ni) {
            if (MODE == 5 && vtile) {
                // transposed v write: vT[b][e][s], e = gc-2048, s = token row in batch
                const int gc = bn + wn + ni*16 + ccol;        // 2048..3071
                const int e  = gc - 2*EMB;
                const int b  = bm >> 11;                      // SQ = 2048
                const int s0 = (bm & (SQ-1)) + wm + mi*16 + crow;
                ushort4 o;
                o.x = f32_to_bf16(acc[mi][ni][0]);
                o.y = f32_to_bf16(acc[mi][ni][1]);
                o.z = f32_to_bf16(acc[mi][ni][2]);
                o.w = f32_to_bf16(acc[mi][ni][3]);
                *(ushort4*)(Vt + ((long)(b*EMB + e)) * SQ + s0) = o;
                continue;
            }
            #pragma unroll
            for (int r = 0; r < 4; ++r) {
                const int gr = bm + wm + mi*16 + crow + r;
                const int gc = bn + wn + ni*16 + ccol;
                const float v = acc[mi][ni][r];
                const long idx = (long)gr * ldc + gc;
                if (MODE == 0 || MODE == 5) {
                    ((unsigned short*)C)[(long)bz*sC + idx] = f32_to_bf16(v);
                } else if (MODE == 1) {
                    const unsigned short p = f32_to_bf16(__expf(v - 16.0f));
                    ((unsigned short*)C)[(long)bz*sC + idx] = p;
                    psum[mi][r] += bf16_to_f32(p);   // sum the ROUNDED value (matches K4 read)
                } else if (MODE == 3) {
                    ((unsigned short*)C)[(long)bz*sC + idx] = f32_to_bf16(v * rinv[mi][r]);
                } else {   // MODE 2
                    const float o = bf16_to_f32(Obf[idx]);
                    const float g = 1.0f / (1.0f + __expf(-v));
                    Fout[idx] = g * o;
                }
            }
        }
    }

    if (MODE == 1) {
        // reduce across the 16 ccol lanes of each crow group, 1 atomic per group
        #pragma unroll
        for (int mi = 0; mi < 4; ++mi) {
            #pragma unroll
            for (int r = 0; r < 4; ++r) {
                float s_ = psum[mi][r];
                s_ += __shfl_xor(s_, 1);
                s_ += __shfl_xor(s_, 2);
                s_ += __shfl_xor(s_, 4);
                s_ += __shfl_xor(s_, 8);
                if ((l & 15) == 0)
                    atomicAdd(&Sf[(long)bz * SQ + bm + wm + mi*16 + crow + r], s_);
            }
        }
    }
}

extern "C" void kernel_launch(void* const* d_in, const int* in_sizes, int n_in,
                              void* d_out, int out_size, void* d_ws, size_t ws_size,
                              hipStream_t stream) {
    const float* rot = (const float*)d_in[0];   // (3E, E) row-major
    const float* ent = (const float*)d_in[1];   // (E, E)
    const float* x   = (const float*)d_in[2];   // (B, S, E)
    const float* gw  = (const float*)d_in[3];   // (E, E)
    float* outp = (float*)d_out;
    char* ws = (char*)d_ws;

    size_t off = 0;
    unsigned short* x_bf    = (unsigned short*)(ws + off); off += (size_t)TOK*EMB*2;     // 16 MB
    unsigned short* wqkv_bf = (unsigned short*)(ws + off); off += (size_t)3*EMB*EMB*2;   // 6 MB
    unsigned short* wout_bf = (unsigned short*)(ws + off); off += (size_t)EMB*EMB*2;     // 2 MB
    unsigned short* gate_bf = (unsigned short*)(ws + off); off += (size_t)EMB*EMB*2;     // 2 MB
    unsigned short* qkv_bf  = (unsigned short*)(ws + off); off += (size_t)TOK*3*EMB*2;   // 48 MB
    unsigned short* vT_bf   = (unsigned short*)(ws + off); off += (size_t)NB*EMB*SQ*2;   // 16 MB
    unsigned short* p_bf    = (unsigned short*)(ws + off); off += (size_t)NB*SQ*SQ*2;    // 32 MB (P)
    float*          sf      = (float*)(ws + off);          off += (size_t)NB*SQ*4;       // 32 KB
    // Aliases (lifetimes disjoint, all launches sequential on one stream):
    unsigned short* ao_bf   = x_bf;                          // x dead after K1; ao live K4->K5
    unsigned short* out_bf  = qkv_bf + (size_t)NB*SQ*SQ;     // qkv dead after K2; out live K5->K6

    // K0: all converts + Sf zeroing in one launch
    convert_all_kernel<<<dim3(TOK*EMB/4/256 + 5*EMB*EMB/4/256 + NB*SQ/4/256), dim3(256),
                         0, stream>>>(x, x_bf, rot, ent, gw, wqkv_bf, sf);

    // K1: qkv = x @ w_qkv^T (8192 x 3072, K=1024); q,k -> qkv_bf, v -> vT_bf transposed
    //     [1536 blocks, TN=128]
    gemm_nt_128<5,128><<<dim3(TOK/128, 3*EMB/128, 1), dim3(256), 0, stream>>>(
        x_bf, wqkv_bf, qkv_bf, nullptr, nullptr, nullptr, vT_bf,
        TOK, 3*EMB, EMB, EMB, EMB, 3*EMB, 0, 0, 0);

    // K2: P = exp(q @ k^T - 16) per batch (2048 x 2048, K=1024) -> bf16 P + row sums
    //     [1024 blocks, TN=128]
    gemm_nt_128<1,128><<<dim3(SQ/128, SQ/128, NB), dim3(256), 0, stream>>>(
        qkv_bf, qkv_bf + EMB, p_bf, nullptr, nullptr, sf, nullptr,
        SQ, SQ, EMB, 3*EMB, 3*EMB, SQ,
        (long)SQ*3*EMB, (long)SQ*3*EMB, (long)SQ*SQ);

    // K4: attn_out = (P @ v) / rowsum per batch (2048 x 1024, K=2048); B = vT (NT form)
    //     [1024 blocks, TN=64: 4 blocks/CU vs 2]
    gemm_nt_128<3,64><<<dim3(SQ/128, EMB/64, NB), dim3(256), 0, stream>>>(
        p_bf, vT_bf, ao_bf, nullptr, nullptr, sf, nullptr,
        SQ, EMB, SQ, SQ, SQ, EMB,
        (long)SQ*SQ, (long)EMB*SQ, (long)SQ*EMB);

    // K5: out = attn_out @ w_out^T (8192 x 1024, K=1024) -> bf16  [1024 blocks, TN=64]
    gemm_nt_128<0,64><<<dim3(TOK/128, EMB/64, 1), dim3(256), 0, stream>>>(
        ao_bf, wout_bf, out_bf, nullptr, nullptr, nullptr, nullptr,
        TOK, EMB, EMB, EMB, EMB, EMB, 0, 0, 0);

    // K6: result = sigmoid(out @ gate_w^T) * out_bf -> fp32 d_out  [1024 blocks, TN=64]
    gemm_nt_128<2,64><<<dim3(TOK/128, EMB/64, 1), dim3(256), 0, stream>>>(
        out_bf, gate_bf, nullptr, out_bf, outp, nullptr, nullptr,
        TOK, EMB, EMB, EMB, EMB, EMB, 0, 0, 0);
}